// Round 7
// baseline (118.373 us; speedup 1.0000x reference)
//
#include <hip/hip_runtime.h>

#define BATCH 8
#define NPTS 4096
#define TOTQ (BATCH * NPTS)
#define TPB 256
#define BIGD 1e30f

// ---- shared arithmetic: bitwise identical between scan and rescan ----
// candidate m as (cx,cy,cz,w) = (-2x, -2y, -2z, x^2+y^2+z^2); -2.0f*x is exact.
// key(n,m) = w_m - 2*dot(p_n,p_m) = d^2 - |p_n|^2 (monotone in d, 3 FMAs)
__device__ __forceinline__ float cand_w(float x, float y, float z) {
    return fmaf(x, x, fmaf(y, y, z * z));
}
__device__ __forceinline__ float cand_key(float cx, float cy, float cz, float w,
                                          float xn, float yn, float zn) {
    return fmaf(cx, xn, fmaf(cy, yn, fmaf(cz, zn, w)));
}

// Stable top-2 (min) with payload, strict < (feed ascending index = jax rule).
__device__ __forceinline__ void top2min(float k, int m,
                                        float& b1, int& i1,
                                        float& b2, int& i2) {
    bool c1 = k < b1;
    bool c2 = k < b2;
    int ni2 = c2 ? m : i2;
    i2 = c1 ? i1 : ni2;
    i1 = c1 ? m : i1;
    b2 = fminf(fmaxf(k, b1), b2);
    b1 = fminf(k, b1);
}

// Lexicographic (value, index) top-2 — final combine only (order-independent).
__device__ __forceinline__ void top2lex(float k, int m,
                                        float& b1, int& i1,
                                        float& b2, int& i2) {
    bool c1 = (k < b1) || (k == b1 && m < i1);
    bool c2 = (k < b2) || (k == b2 && m < i2);
    float nb2 = c1 ? b1 : (c2 ? k : b2);
    int   ni2 = c1 ? i1 : (c2 ? m : i2);
    b1 = c1 ? k : b1;
    i1 = c1 ? m : i1;
    b2 = nb2;
    i2 = ni2;
}

// Pass 1: per (query, chunk) track v1 WITH index + v2 value-only: 7 VALU/pair.
// No self exclusion (self key is the strict chunk min -> occupies v1, i1=n;
// merge skips self-chunk entries). block = (query tile TPB*Q, chunk, batch).
template <int NCHUNKS, int Q>
__global__ __launch_bounds__(TPB, 4) void knn_scan(const float* __restrict__ coords,
                                                   float2* __restrict__ vals,
                                                   int* __restrict__ idx1) {
    constexpr int CHUNKSZ = NPTS / NCHUNKS;
    __shared__ float4 pts[CHUNKSZ];
    const int tid   = (int)threadIdx.x;
    const int tile  = blockIdx.x;
    const int chunk = blockIdx.y;
    const int b     = blockIdx.z;
    const float* basep = coords + (size_t)b * NPTS * 3;
    const int mbase = chunk * CHUNKSZ;

    for (int p = tid; p < CHUNKSZ; p += TPB) {
        float x = basep[(mbase + p) * 3 + 0];
        float y = basep[(mbase + p) * 3 + 1];
        float z = basep[(mbase + p) * 3 + 2];
        pts[p] = make_float4(-2.0f * x, -2.0f * y, -2.0f * z, cand_w(x, y, z));
    }

    const int qbase = tile * (TPB * Q);
    float xn[Q], yn[Q], zn[Q], b1[Q], b2[Q];
    int i1[Q];
#pragma unroll
    for (int q = 0; q < Q; ++q) {
        int n = qbase + q * TPB + tid;
        xn[q] = basep[n * 3 + 0];
        yn[q] = basep[n * 3 + 1];
        zn[q] = basep[n * 3 + 2];
        b1[q] = BIGD; b2[q] = BIGD; i1[q] = 0;
    }
    __syncthreads();

    for (int p = 0; p < CHUNKSZ; p += 8) {
        float4 c[8];
#pragma unroll
        for (int j = 0; j < 8; ++j) c[j] = pts[p + j];
#pragma unroll
        for (int j = 0; j < 8; ++j) {
            const int m = mbase + p + j;   // wave-uniform -> SGPR operand
#pragma unroll
            for (int q = 0; q < Q; ++q) {
                float k = cand_key(c[j].x, c[j].y, c[j].z, c[j].w, xn[q], yn[q], zn[q]);
                bool c1 = k < b1[q];
                i1[q] = c1 ? m : i1[q];
                b2[q] = fminf(fmaxf(k, b1[q]), b2[q]);  // uses old b1
                b1[q] = fminf(k, b1[q]);
            }
        }
    }

#pragma unroll
    for (int q = 0; q < Q; ++q) {
        int gq = (size_t)0 + b * NPTS + qbase + q * TPB + tid;
        vals[(size_t)chunk * TOTQ + gq] = make_float2(b1[q], b2[q]);
        idx1[(size_t)chunk * TOTQ + gq] = i1[q];
    }
}

// Rescan one chunk from GLOBAL coords with index tracking, bitwise identical
// arithmetic, self-excluded. Wave-uniform c -> broadcast loads (L1 hit).
template <int CHUNKSZ>
__device__ __forceinline__ void rescan_global(const float* __restrict__ basep, int c, int n,
                                              float xn, float yn, float zn,
                                              float& r1, int& j1, float& r2, int& j2) {
    r1 = BIGD; r2 = BIGD; j1 = 0; j2 = 0;
    const int m0 = c * CHUNKSZ;
    for (int m = m0; m < m0 + CHUNKSZ; ++m) {
        float x = basep[m * 3 + 0];
        float y = basep[m * 3 + 1];
        float z = basep[m * 3 + 2];
        float w = cand_w(x, y, z);
        float k = cand_key(-2.0f * x, -2.0f * y, -2.0f * z, w, xn, yn, zn);
        k = (m == n) ? BIGD : k;
        top2min(k, m, r1, j1, r2, j2);
    }
}

// Pass 2: value-merge 63 non-self chunks with tags (2c | slot); resolve
// indices via idx1 loads (slot 0) or rare chunk rescans (slot 1); always
// rescan the wave-uniform self chunk; lexicographic final combine.
template <int NCHUNKS>
__global__ __launch_bounds__(TPB) void knn_merge(const float* __restrict__ coords,
                                                 const float2* __restrict__ vals,
                                                 const int* __restrict__ idx1,
                                                 float* __restrict__ out) {
    constexpr int CHUNKSZ = NPTS / NCHUNKS;
    const int q = blockIdx.x * TPB + (int)threadIdx.x;  // 0..TOTQ-1
    const int b = q >> 12;
    const int n = q & (NPTS - 1);
    const float* basep = coords + (size_t)b * NPTS * 3;
    const int c_self = n / CHUNKSZ;   // wave-uniform (CHUNKSZ >= 64)

    const float xn = basep[n * 3 + 0];
    const float yn = basep[n * 3 + 1];
    const float zn = basep[n * 3 + 2];

    // Tagged value merge, self chunk skipped (wave-uniform branch).
    float f1 = BIGD, f2 = BIGD;
    int ta = 0, tb = 0;
#pragma unroll 8
    for (int c = 0; c < NCHUNKS; ++c) {
        if (c == c_self) continue;
        float2 v = vals[(size_t)c * TOTQ + q];
        top2min(v.x, 2 * c + 0, f1, ta, f2, tb);
        top2min(v.y, 2 * c + 1, f1, ta, f2, tb);
    }
    const int ct1 = ta >> 1, s1 = ta & 1;
    const int ct2 = tb >> 1, s2 = tb & 1;

    float r1, r2; int j1, j2;
    int g1, g2;
    // f1 is always a v1 slot (v1[c] <= v2[c], fed first); branch kept for safety.
    if (s1 == 0) {
        g1 = idx1[(size_t)ct1 * TOTQ + q];
    } else {
        rescan_global<CHUNKSZ>(basep, ct1, n, xn, yn, zn, r1, j1, r2, j2);
        g1 = j2;
    }
    // f2 from a v2 slot only when both NNs share chunk ct2 (~1.5%): rescan it.
    if (s2 == 0) {
        g2 = idx1[(size_t)ct2 * TOTQ + q];
    } else {
        rescan_global<CHUNKSZ>(basep, ct2, n, xn, yn, zn, r1, j1, r2, j2);
        g2 = j2;
    }

    // Self chunk: always rescan (wave-uniform -> broadcast loads).
    float rs1, rs2; int js1, js2;
    rescan_global<CHUNKSZ>(basep, c_self, n, xn, yn, zn, rs1, js1, rs2, js2);

    // Final exact lexicographic combine.
    float o1 = BIGD, o2 = BIGD;
    int h1 = 0x7fffffff, h2 = 0x7fffffff;
    top2lex(f1, g1, o1, h1, o2, h2);
    top2lex(f2, g2, o1, h1, o2, h2);
    top2lex(rs1, js1, o1, h1, o2, h2);
    top2lex(rs2, js2, o1, h1, o2, h2);

    float* A  = out;
    float* C  = out + (size_t)TOTQ * 3;
    float* I1 = out + (size_t)2 * TOTQ * 3;
    float* I2 = I1 + (size_t)TOTQ;

    A[(size_t)q * 3 + 0] = basep[h1 * 3 + 0];
    A[(size_t)q * 3 + 1] = basep[h1 * 3 + 1];
    A[(size_t)q * 3 + 2] = basep[h1 * 3 + 2];
    C[(size_t)q * 3 + 0] = basep[h2 * 3 + 0];
    C[(size_t)q * 3 + 1] = basep[h2 * 3 + 1];
    C[(size_t)q * 3 + 2] = basep[h2 * 3 + 2];
    I1[q] = (float)h1;
    I2[q] = (float)h2;
}

// Ultimate fallback (tiny ws): monolithic kernel, all candidates in LDS.
__global__ __launch_bounds__(TPB) void knn_full(const float* __restrict__ coords,
                                                float* __restrict__ out) {
    __shared__ float4 pts[NPTS];  // 64 KB
    const int tid  = (int)threadIdx.x;
    const int tile = blockIdx.x;
    const int b    = blockIdx.y;
    const float* basep = coords + (size_t)b * NPTS * 3;

    for (int p = tid; p < NPTS; p += TPB) {
        float x = basep[p * 3 + 0];
        float y = basep[p * 3 + 1];
        float z = basep[p * 3 + 2];
        pts[p] = make_float4(-2.0f * x, -2.0f * y, -2.0f * z, cand_w(x, y, z));
    }
    const int n = tile * TPB + tid;
    const float xn = basep[n * 3 + 0];
    const float yn = basep[n * 3 + 1];
    const float zn = basep[n * 3 + 2];
    __syncthreads();

    float b1 = BIGD, b2 = BIGD;
    int i1 = 0, i2 = 0;
    for (int p = 0; p < NPTS; p += 4) {
#pragma unroll
        for (int j = 0; j < 4; ++j) {
            float4 c = pts[p + j];
            float k = cand_key(c.x, c.y, c.z, c.w, xn, yn, zn);
            k = (p + j == n) ? BIGD : k;
            top2min(k, p + j, b1, i1, b2, i2);
        }
    }

    const int q = b * NPTS + n;
    float* A  = out;
    float* C  = out + (size_t)TOTQ * 3;
    float* I1 = out + (size_t)2 * TOTQ * 3;
    float* I2 = I1 + (size_t)TOTQ;
    float4 p1 = pts[i1];
    float4 p2 = pts[i2];
    A[(size_t)q * 3 + 0] = -0.5f * p1.x;
    A[(size_t)q * 3 + 1] = -0.5f * p1.y;
    A[(size_t)q * 3 + 2] = -0.5f * p1.z;
    C[(size_t)q * 3 + 0] = -0.5f * p2.x;
    C[(size_t)q * 3 + 1] = -0.5f * p2.y;
    C[(size_t)q * 3 + 2] = -0.5f * p2.z;
    I1[q] = (float)i1;
    I2[q] = (float)i2;
}

extern "C" void kernel_launch(void* const* d_in, const int* in_sizes, int n_in,
                              void* d_out, int out_size, void* d_ws, size_t ws_size,
                              hipStream_t stream) {
    const float* coords = (const float*)d_in[0];
    float* out = (float*)d_out;

    // ws layout: float2 vals[NCHUNKS][TOTQ] then int idx1[NCHUNKS][TOTQ]
    if (ws_size >= (size_t)64 * TOTQ * (sizeof(float2) + sizeof(int))) {
        float2* vals = (float2*)d_ws;
        int* idx1 = (int*)((char*)d_ws + (size_t)64 * TOTQ * sizeof(float2));
        hipLaunchKernelGGL((knn_scan<64, 8>), dim3(2, 64, BATCH), dim3(TPB), 0, stream,
                           coords, vals, idx1);
        hipLaunchKernelGGL((knn_merge<64>), dim3(TOTQ / TPB), dim3(TPB), 0, stream,
                           coords, vals, idx1, out);
    } else if (ws_size >= (size_t)32 * TOTQ * (sizeof(float2) + sizeof(int))) {
        float2* vals = (float2*)d_ws;
        int* idx1 = (int*)((char*)d_ws + (size_t)32 * TOTQ * sizeof(float2));
        hipLaunchKernelGGL((knn_scan<32, 8>), dim3(2, 32, BATCH), dim3(TPB), 0, stream,
                           coords, vals, idx1);
        hipLaunchKernelGGL((knn_merge<32>), dim3(TOTQ / TPB), dim3(TPB), 0, stream,
                           coords, vals, idx1, out);
    } else {
        hipLaunchKernelGGL(knn_full, dim3(NPTS / TPB, BATCH), dim3(TPB), 0, stream,
                           coords, out);
    }
}

// Round 8
// 113.117 us; speedup vs baseline: 1.0465x; 1.0465x over previous
//
#include <hip/hip_runtime.h>

#define BATCH 8
#define NPTS 4096
#define TOTQ (BATCH * NPTS)
#define TPB 256
#define BIGD 1e30f

// Stable top-2 (min) with payload. Invariant b1 <= b2. Strict < keeps the
// earlier-fed candidate on ties (== jax.lax.top_k lowest-index rule when
// candidates are fed in ascending index order).
__device__ __forceinline__ void top2min(float k, int m,
                                        float& b1, int& i1,
                                        float& b2, int& i2) {
    bool c1 = k < b1;
    bool c2 = k < b2;
    int ni2 = c2 ? m : i2;
    i2 = c1 ? i1 : ni2;
    i1 = c1 ? m : i1;
    b2 = fminf(fmaxf(k, b1), b2);   // med3(b1,b2,k) given b1<=b2
    b1 = fminf(k, b1);
}

// Inner scan over one LDS-staged chunk, full index tracking.
// EXC: block's query tile overlaps its candidate chunk -> mask self per pair.
// Key k = |p_m|^2 - 2*dot(p_n,p_m) = d^2 - |p_n|^2: monotone in d, 3 FMAs.
template <int CHUNKSZ, int Q, bool EXC>
__device__ __forceinline__ void scan_loop(const float4* __restrict__ pts, int mbase,
                                          const int* nq,
                                          const float* xn, const float* yn, const float* zn,
                                          float* b1, int* i1, float* b2, int* i2) {
    for (int p = 0; p < CHUNKSZ; p += 4) {
        float4 c[4];
#pragma unroll
        for (int j = 0; j < 4; ++j) c[j] = pts[p + j];
#pragma unroll
        for (int j = 0; j < 4; ++j) {
            const int m = mbase + p + j;   // wave-uniform (SGPR)
#pragma unroll
            for (int q = 0; q < Q; ++q) {
                float k = fmaf(c[j].x, xn[q], fmaf(c[j].y, yn[q], fmaf(c[j].z, zn[q], c[j].w)));
                if (EXC) k = (m == nq[q]) ? BIGD : k;
                top2min(k, m, b1[q], i1[q], b2[q], i2[q]);
            }
        }
    }
}

// Pass 1: block = (query tile of TPB*Q, candidate chunk of NPTS/NCHUNKS, batch).
// Partials carry BOTH indices -> merge stays trivial.
template <int NCHUNKS, int Q>
__global__ __launch_bounds__(TPB, 4) void knn_scan(const float* __restrict__ coords,
                                                   float4* __restrict__ partial) {
    constexpr int CHUNKSZ = NPTS / NCHUNKS;
    __shared__ float4 pts[CHUNKSZ];
    const int tid   = (int)threadIdx.x;
    const int tile  = blockIdx.x;
    const int chunk = blockIdx.y;
    const int b     = blockIdx.z;
    const float* basep = coords + (size_t)b * NPTS * 3;
    const int mbase = chunk * CHUNKSZ;

    // Stage (-2x, -2y, -2z, |p|^2); -2.0f*x is exact.
    for (int p = tid; p < CHUNKSZ; p += TPB) {
        float x = basep[(mbase + p) * 3 + 0];
        float y = basep[(mbase + p) * 3 + 1];
        float z = basep[(mbase + p) * 3 + 2];
        pts[p] = make_float4(-2.0f * x, -2.0f * y, -2.0f * z,
                             fmaf(x, x, fmaf(y, y, z * z)));
    }

    const int qbase = tile * (TPB * Q);
    int nq[Q];
    float xn[Q], yn[Q], zn[Q], b1[Q], b2[Q];
    int i1[Q], i2[Q];
#pragma unroll
    for (int q = 0; q < Q; ++q) {
        int n = qbase + q * TPB + tid;
        nq[q] = n;
        xn[q] = basep[n * 3 + 0];
        yn[q] = basep[n * 3 + 1];
        zn[q] = basep[n * 3 + 2];
        b1[q] = BIGD; b2[q] = BIGD; i1[q] = 0; i2[q] = 0;
    }
    __syncthreads();

    // Block-uniform overlap test picks the EXC instantiation.
    const int qend = qbase + TPB * Q;
    const int mend = mbase + CHUNKSZ;
    if (mbase < qend && qbase < mend) {
        scan_loop<CHUNKSZ, Q, true >(pts, mbase, nq, xn, yn, zn, b1, i1, b2, i2);
    } else {
        scan_loop<CHUNKSZ, Q, false>(pts, mbase, nq, xn, yn, zn, b1, i1, b2, i2);
    }

    // Layout [chunk][global query] -> coalesced in both passes.
#pragma unroll
    for (int q = 0; q < Q; ++q) {
        int n = qbase + q * TPB + tid;
        partial[(size_t)chunk * TOTQ + (size_t)b * NPTS + n] =
            make_float4(b1[q], __int_as_float(i1[q]), b2[q], __int_as_float(i2[q]));
    }
}

// Pass 2: trivial merge of NCHUNKS indexed partials per query (ascending
// chunk = ascending index = stable), gather coords, write outputs.
template <int NCHUNKS>
__global__ __launch_bounds__(TPB) void knn_merge(const float* __restrict__ coords,
                                                 const float4* __restrict__ partial,
                                                 float* __restrict__ out) {
    const int q = blockIdx.x * TPB + (int)threadIdx.x;  // 0..TOTQ-1
    const int b = q >> 12;
    float b1 = BIGD, b2 = BIGD;
    int i1 = 0, i2 = 0;
#pragma unroll 8
    for (int c = 0; c < NCHUNKS; ++c) {
        float4 pc = partial[(size_t)c * TOTQ + q];
        top2min(pc.x, __float_as_int(pc.y), b1, i1, b2, i2);
        top2min(pc.z, __float_as_int(pc.w), b1, i1, b2, i2);
    }
    const float* basep = coords + (size_t)b * NPTS * 3;
    float* A  = out;
    float* C  = out + (size_t)TOTQ * 3;
    float* I1 = out + (size_t)2 * TOTQ * 3;
    float* I2 = I1 + (size_t)TOTQ;

    A[(size_t)q * 3 + 0] = basep[i1 * 3 + 0];
    A[(size_t)q * 3 + 1] = basep[i1 * 3 + 1];
    A[(size_t)q * 3 + 2] = basep[i1 * 3 + 2];
    C[(size_t)q * 3 + 0] = basep[i2 * 3 + 0];
    C[(size_t)q * 3 + 1] = basep[i2 * 3 + 1];
    C[(size_t)q * 3 + 2] = basep[i2 * 3 + 2];
    I1[q] = (float)i1;
    I2[q] = (float)i2;
}

// Fallback (tiny ws): monolithic kernel, all candidates in LDS.
__global__ __launch_bounds__(TPB) void knn_full(const float* __restrict__ coords,
                                                float* __restrict__ out) {
    __shared__ float4 pts[NPTS];  // 64 KB
    const int tid  = (int)threadIdx.x;
    const int tile = blockIdx.x;
    const int b    = blockIdx.y;
    const float* basep = coords + (size_t)b * NPTS * 3;

    for (int p = tid; p < NPTS; p += TPB) {
        float x = basep[p * 3 + 0];
        float y = basep[p * 3 + 1];
        float z = basep[p * 3 + 2];
        pts[p] = make_float4(-2.0f * x, -2.0f * y, -2.0f * z,
                             fmaf(x, x, fmaf(y, y, z * z)));
    }
    const int n = tile * TPB + tid;
    const float xn = basep[n * 3 + 0];
    const float yn = basep[n * 3 + 1];
    const float zn = basep[n * 3 + 2];
    __syncthreads();

    float b1 = BIGD, b2 = BIGD;
    int i1 = 0, i2 = 0;
    for (int p = 0; p < NPTS; p += 4) {
#pragma unroll
        for (int j = 0; j < 4; ++j) {
            float4 c = pts[p + j];
            float k = fmaf(c.x, xn, fmaf(c.y, yn, fmaf(c.z, zn, c.w)));
            k = (p + j == n) ? BIGD : k;
            top2min(k, p + j, b1, i1, b2, i2);
        }
    }

    const int q = b * NPTS + n;
    float* A  = out;
    float* C  = out + (size_t)TOTQ * 3;
    float* I1 = out + (size_t)2 * TOTQ * 3;
    float* I2 = I1 + (size_t)TOTQ;
    float4 p1 = pts[i1];
    float4 p2 = pts[i2];
    A[(size_t)q * 3 + 0] = -0.5f * p1.x;
    A[(size_t)q * 3 + 1] = -0.5f * p1.y;
    A[(size_t)q * 3 + 2] = -0.5f * p1.z;
    C[(size_t)q * 3 + 0] = -0.5f * p2.x;
    C[(size_t)q * 3 + 1] = -0.5f * p2.y;
    C[(size_t)q * 3 + 2] = -0.5f * p2.z;
    I1[q] = (float)i1;
    I2[q] = (float)i2;
}

extern "C" void kernel_launch(void* const* d_in, const int* in_sizes, int n_in,
                              void* d_out, int out_size, void* d_ws, size_t ws_size,
                              hipStream_t stream) {
    const float* coords = (const float*)d_in[0];
    float* out = (float*)d_out;
    float4* partial = (float4*)d_ws;
    const size_t chunk_bytes = (size_t)TOTQ * sizeof(float4);  // 512 KB per chunk

    if (ws_size >= 64 * chunk_bytes) {
        // 32 MB: NCHUNKS=64, Q=8 -> grid 2*64*8 = 1024 blocks (4/CU, 4 waves/SIMD)
        hipLaunchKernelGGL((knn_scan<64, 8>), dim3(2, 64, BATCH), dim3(TPB), 0, stream,
                           coords, partial);
        hipLaunchKernelGGL((knn_merge<64>), dim3(TOTQ / TPB), dim3(TPB), 0, stream,
                           coords, partial, out);
    } else if (ws_size >= 32 * chunk_bytes) {
        // 16 MB: NCHUNKS=32, Q=8 -> 512 blocks
        hipLaunchKernelGGL((knn_scan<32, 8>), dim3(2, 32, BATCH), dim3(TPB), 0, stream,
                           coords, partial);
        hipLaunchKernelGGL((knn_merge<32>), dim3(TOTQ / TPB), dim3(TPB), 0, stream,
                           coords, partial, out);
    } else {
        hipLaunchKernelGGL(knn_full, dim3(NPTS / TPB, BATCH), dim3(TPB), 0, stream,
                           coords, out);
    }
}

// Round 9
// 106.421 us; speedup vs baseline: 1.1123x; 1.0629x over previous
//
#include <hip/hip_runtime.h>

#define BATCH 8
#define NPTS 4096
#define TOTQ (BATCH * NPTS)
#define TPB 256
#define BIGD 1e30f

// Stable top-2 (min) with payload — C++ version (merge/fallback use this).
__device__ __forceinline__ void top2min(float k, int m,
                                        float& b1, int& i1,
                                        float& b2, int& i2) {
    bool c1 = k < b1;
    bool c2 = k < b2;
    int ni2 = c2 ? m : i2;
    i2 = c1 ? i1 : ni2;
    i1 = c1 ? m : i1;
    b2 = fminf(fmaxf(k, b1), b2);
    b1 = fminf(k, b1);
}

// Forced 7-instruction top-2 update. Semantics identical to top2min:
//   c1 = k<b1 (sgpr pair), c2 = k<b2 (vcc)
//   t  = c2 ? m : i2 ; i2 = c1 ? i1 : t ; i1 = c1 ? m : i1
//   b2 = med3(k,b1,b2)  (== min(max(k,b1),b2) given b1<=b2) ; b1 = min(k,b1)
__device__ __forceinline__ void top2min_asm(float k, int m,
                                            float& b1, int& i1,
                                            float& b2, int& i2) {
    int t;
    unsigned long long c1;
    asm("v_cmp_lt_f32 %[c1], %[k], %[b1]\n\t"
        "v_cmp_lt_f32 vcc, %[k], %[b2]\n\t"
        "v_cndmask_b32 %[t], %[i2], %[m], vcc\n\t"
        "v_cndmask_b32 %[i2], %[t], %[i1], %[c1]\n\t"
        "v_cndmask_b32 %[i1], %[i1], %[m], %[c1]\n\t"
        "v_med3_f32 %[b2], %[k], %[b1], %[b2]\n\t"
        "v_min_f32 %[b1], %[k], %[b1]"
        : [b1] "+v"(b1), [i1] "+v"(i1), [b2] "+v"(b2), [i2] "+v"(i2),
          [t] "=&v"(t), [c1] "=&s"(c1)
        : [k] "v"(k), [m] "v"(m)
        : "vcc");
}

// Inner scan over one LDS-staged chunk, full index tracking via asm update.
// EXC: block's query tile overlaps its candidate chunk -> mask self per pair.
// Key k = |p_m|^2 - 2*dot(p_n,p_m) = d^2 - |p_n|^2: monotone in d, 3 FMAs.
template <int CHUNKSZ, int Q, bool EXC>
__device__ __forceinline__ void scan_loop(const float4* __restrict__ pts, int mbase,
                                          const int* nq,
                                          const float* xn, const float* yn, const float* zn,
                                          float* b1, int* i1, float* b2, int* i2) {
    for (int p = 0; p < CHUNKSZ; p += 4) {
        float4 c[4];
#pragma unroll
        for (int j = 0; j < 4; ++j) c[j] = pts[p + j];
#pragma unroll
        for (int j = 0; j < 4; ++j) {
            const int m = mbase + p + j;
#pragma unroll
            for (int q = 0; q < Q; ++q) {
                float k = fmaf(c[j].x, xn[q], fmaf(c[j].y, yn[q], fmaf(c[j].z, zn[q], c[j].w)));
                if (EXC) k = (m == nq[q]) ? BIGD : k;
                top2min_asm(k, m, b1[q], i1[q], b2[q], i2[q]);
            }
        }
    }
}

// Pass 1: block = (query tile of TPB*Q, candidate chunk of NPTS/NCHUNKS, batch).
// Partials carry BOTH indices -> merge stays trivial.
template <int NCHUNKS, int Q>
__global__ __launch_bounds__(TPB, 4) void knn_scan(const float* __restrict__ coords,
                                                   float4* __restrict__ partial) {
    constexpr int CHUNKSZ = NPTS / NCHUNKS;
    __shared__ float4 pts[CHUNKSZ];
    const int tid   = (int)threadIdx.x;
    const int tile  = blockIdx.x;
    const int chunk = blockIdx.y;
    const int b     = blockIdx.z;
    const float* basep = coords + (size_t)b * NPTS * 3;
    const int mbase = chunk * CHUNKSZ;

    // Stage (-2x, -2y, -2z, |p|^2); -2.0f*x is exact.
    for (int p = tid; p < CHUNKSZ; p += TPB) {
        float x = basep[(mbase + p) * 3 + 0];
        float y = basep[(mbase + p) * 3 + 1];
        float z = basep[(mbase + p) * 3 + 2];
        pts[p] = make_float4(-2.0f * x, -2.0f * y, -2.0f * z,
                             fmaf(x, x, fmaf(y, y, z * z)));
    }

    const int qbase = tile * (TPB * Q);
    int nq[Q];
    float xn[Q], yn[Q], zn[Q], b1[Q], b2[Q];
    int i1[Q], i2[Q];
#pragma unroll
    for (int q = 0; q < Q; ++q) {
        int n = qbase + q * TPB + tid;
        nq[q] = n;
        xn[q] = basep[n * 3 + 0];
        yn[q] = basep[n * 3 + 1];
        zn[q] = basep[n * 3 + 2];
        b1[q] = BIGD; b2[q] = BIGD; i1[q] = 0; i2[q] = 0;
    }
    __syncthreads();

    // Block-uniform overlap test picks the EXC instantiation.
    const int qend = qbase + TPB * Q;
    const int mend = mbase + CHUNKSZ;
    if (mbase < qend && qbase < mend) {
        scan_loop<CHUNKSZ, Q, true >(pts, mbase, nq, xn, yn, zn, b1, i1, b2, i2);
    } else {
        scan_loop<CHUNKSZ, Q, false>(pts, mbase, nq, xn, yn, zn, b1, i1, b2, i2);
    }

    // Layout [chunk][global query] -> coalesced in both passes.
#pragma unroll
    for (int q = 0; q < Q; ++q) {
        int n = qbase + q * TPB + tid;
        partial[(size_t)chunk * TOTQ + (size_t)b * NPTS + n] =
            make_float4(b1[q], __int_as_float(i1[q]), b2[q], __int_as_float(i2[q]));
    }
}

// Pass 2: trivial merge of NCHUNKS indexed partials per query (ascending
// chunk = ascending index = stable), gather coords, write outputs.
template <int NCHUNKS>
__global__ __launch_bounds__(TPB) void knn_merge(const float* __restrict__ coords,
                                                 const float4* __restrict__ partial,
                                                 float* __restrict__ out) {
    const int q = blockIdx.x * TPB + (int)threadIdx.x;  // 0..TOTQ-1
    const int b = q >> 12;
    float b1 = BIGD, b2 = BIGD;
    int i1 = 0, i2 = 0;
#pragma unroll 8
    for (int c = 0; c < NCHUNKS; ++c) {
        float4 pc = partial[(size_t)c * TOTQ + q];
        top2min(pc.x, __float_as_int(pc.y), b1, i1, b2, i2);
        top2min(pc.z, __float_as_int(pc.w), b1, i1, b2, i2);
    }
    const float* basep = coords + (size_t)b * NPTS * 3;
    float* A  = out;
    float* C  = out + (size_t)TOTQ * 3;
    float* I1 = out + (size_t)2 * TOTQ * 3;
    float* I2 = I1 + (size_t)TOTQ;

    A[(size_t)q * 3 + 0] = basep[i1 * 3 + 0];
    A[(size_t)q * 3 + 1] = basep[i1 * 3 + 1];
    A[(size_t)q * 3 + 2] = basep[i1 * 3 + 2];
    C[(size_t)q * 3 + 0] = basep[i2 * 3 + 0];
    C[(size_t)q * 3 + 1] = basep[i2 * 3 + 1];
    C[(size_t)q * 3 + 2] = basep[i2 * 3 + 2];
    I1[q] = (float)i1;
    I2[q] = (float)i2;
}

// Fallback (tiny ws): monolithic kernel, all candidates in LDS.
__global__ __launch_bounds__(TPB) void knn_full(const float* __restrict__ coords,
                                                float* __restrict__ out) {
    __shared__ float4 pts[NPTS];  // 64 KB
    const int tid  = (int)threadIdx.x;
    const int tile = blockIdx.x;
    const int b    = blockIdx.y;
    const float* basep = coords + (size_t)b * NPTS * 3;

    for (int p = tid; p < NPTS; p += TPB) {
        float x = basep[p * 3 + 0];
        float y = basep[p * 3 + 1];
        float z = basep[p * 3 + 2];
        pts[p] = make_float4(-2.0f * x, -2.0f * y, -2.0f * z,
                             fmaf(x, x, fmaf(y, y, z * z)));
    }
    const int n = tile * TPB + tid;
    const float xn = basep[n * 3 + 0];
    const float yn = basep[n * 3 + 1];
    const float zn = basep[n * 3 + 2];
    __syncthreads();

    float b1 = BIGD, b2 = BIGD;
    int i1 = 0, i2 = 0;
    for (int p = 0; p < NPTS; p += 4) {
#pragma unroll
        for (int j = 0; j < 4; ++j) {
            float4 c = pts[p + j];
            float k = fmaf(c.x, xn, fmaf(c.y, yn, fmaf(c.z, zn, c.w)));
            k = (p + j == n) ? BIGD : k;
            top2min(k, p + j, b1, i1, b2, i2);
        }
    }

    const int q = b * NPTS + n;
    float* A  = out;
    float* C  = out + (size_t)TOTQ * 3;
    float* I1 = out + (size_t)2 * TOTQ * 3;
    float* I2 = I1 + (size_t)TOTQ;
    float4 p1 = pts[i1];
    float4 p2 = pts[i2];
    A[(size_t)q * 3 + 0] = -0.5f * p1.x;
    A[(size_t)q * 3 + 1] = -0.5f * p1.y;
    A[(size_t)q * 3 + 2] = -0.5f * p1.z;
    C[(size_t)q * 3 + 0] = -0.5f * p2.x;
    C[(size_t)q * 3 + 1] = -0.5f * p2.y;
    C[(size_t)q * 3 + 2] = -0.5f * p2.z;
    I1[q] = (float)i1;
    I2[q] = (float)i2;
}

extern "C" void kernel_launch(void* const* d_in, const int* in_sizes, int n_in,
                              void* d_out, int out_size, void* d_ws, size_t ws_size,
                              hipStream_t stream) {
    const float* coords = (const float*)d_in[0];
    float* out = (float*)d_out;
    float4* partial = (float4*)d_ws;
    const size_t chunk_bytes = (size_t)TOTQ * sizeof(float4);  // 512 KB per chunk

    if (ws_size >= 64 * chunk_bytes) {
        // 32 MB: NCHUNKS=64, Q=8 -> grid 2*64*8 = 1024 blocks (4/CU, 4 waves/SIMD)
        hipLaunchKernelGGL((knn_scan<64, 8>), dim3(2, 64, BATCH), dim3(TPB), 0, stream,
                           coords, partial);
        hipLaunchKernelGGL((knn_merge<64>), dim3(TOTQ / TPB), dim3(TPB), 0, stream,
                           coords, partial, out);
    } else if (ws_size >= 32 * chunk_bytes) {
        // 16 MB: NCHUNKS=32, Q=8 -> 512 blocks
        hipLaunchKernelGGL((knn_scan<32, 8>), dim3(2, 32, BATCH), dim3(TPB), 0, stream,
                           coords, partial);
        hipLaunchKernelGGL((knn_merge<32>), dim3(TOTQ / TPB), dim3(TPB), 0, stream,
                           coords, partial, out);
    } else {
        hipLaunchKernelGGL(knn_full, dim3(NPTS / TPB, BATCH), dim3(TPB), 0, stream,
                           coords, out);
    }
}

// Round 10
// 106.055 us; speedup vs baseline: 1.1161x; 1.0035x over previous
//
#include <hip/hip_runtime.h>

#define BATCH 8
#define NPTS 4096
#define TOTQ (BATCH * NPTS)
#define TPB 256
#define BIGD 1e30f

// Stable top-2 (min) with payload — C++ version (merge/fallback use this).
__device__ __forceinline__ void top2min(float k, int m,
                                        float& b1, int& i1,
                                        float& b2, int& i2) {
    bool c1 = k < b1;
    bool c2 = k < b2;
    int ni2 = c2 ? m : i2;
    i2 = c1 ? i1 : ni2;
    i1 = c1 ? m : i1;
    b2 = fminf(fmaxf(k, b1), b2);
    b1 = fminf(k, b1);
}

// Forced 7-instruction top-2 update. Semantics identical to top2min:
//   c1 = k<b1 (sgpr pair), c2 = k<b2 (vcc)
//   t  = c2 ? m : i2 ; i2 = c1 ? i1 : t ; i1 = c1 ? m : i1
//   b2 = med3(k,b1,b2)  (== min(max(k,b1),b2) given b1<=b2) ; b1 = min(k,b1)
__device__ __forceinline__ void top2min_asm(float k, int m,
                                            float& b1, int& i1,
                                            float& b2, int& i2) {
    int t;
    unsigned long long c1;
    asm("v_cmp_lt_f32 %[c1], %[k], %[b1]\n\t"
        "v_cmp_lt_f32 vcc, %[k], %[b2]\n\t"
        "v_cndmask_b32 %[t], %[i2], %[m], vcc\n\t"
        "v_cndmask_b32 %[i2], %[t], %[i1], %[c1]\n\t"
        "v_cndmask_b32 %[i1], %[i1], %[m], %[c1]\n\t"
        "v_med3_f32 %[b2], %[k], %[b1], %[b2]\n\t"
        "v_min_f32 %[b1], %[k], %[b1]"
        : [b1] "+v"(b1), [i1] "+v"(i1), [b2] "+v"(b2), [i2] "+v"(i2),
          [t] "=&v"(t), [c1] "=&s"(c1)
        : [k] "v"(k), [m] "v"(m)
        : "vcc");
}

// Inner scan over one LDS-staged chunk, full index tracking via asm update.
// EXC: block's query tile overlaps its candidate chunk -> mask self per pair.
// Key k = |p_m|^2 - 2*dot(p_n,p_m) = d^2 - |p_n|^2: monotone in d, 3 FMAs.
template <int CHUNKSZ, int Q, bool EXC>
__device__ __forceinline__ void scan_loop(const float4* __restrict__ pts, int mbase,
                                          const int* nq,
                                          const float* xn, const float* yn, const float* zn,
                                          float* b1, int* i1, float* b2, int* i2) {
    for (int p = 0; p < CHUNKSZ; p += 4) {
        float4 c[4];
#pragma unroll
        for (int j = 0; j < 4; ++j) c[j] = pts[p + j];
#pragma unroll
        for (int j = 0; j < 4; ++j) {
            const int m = mbase + p + j;
#pragma unroll
            for (int q = 0; q < Q; ++q) {
                float k = fmaf(c[j].x, xn[q], fmaf(c[j].y, yn[q], fmaf(c[j].z, zn[q], c[j].w)));
                if (EXC) k = (m == nq[q]) ? BIGD : k;
                top2min_asm(k, m, b1[q], i1[q], b2[q], i2[q]);
            }
        }
    }
}

// Pass 1: block = (query tile of TPB*Q, candidate chunk of NPTS/NCHUNKS, batch).
// Partials carry BOTH indices -> merge stays trivial.
// waves_per_eu(4,4): pin occupancy at exactly 4 waves/EU so the register
// allocator may use the full 128 VGPRs — the Q=8 state (~92 regs) must stay
// resident (R8/R9: allocator chose 64 regs and paid ~9 remat VALU/pair).
template <int NCHUNKS, int Q>
__global__ __launch_bounds__(TPB)
__attribute__((amdgpu_waves_per_eu(4, 4)))
void knn_scan(const float* __restrict__ coords,
              float4* __restrict__ partial) {
    constexpr int CHUNKSZ = NPTS / NCHUNKS;
    __shared__ float4 pts[CHUNKSZ];
    const int tid   = (int)threadIdx.x;
    const int tile  = blockIdx.x;
    const int chunk = blockIdx.y;
    const int b     = blockIdx.z;
    const float* basep = coords + (size_t)b * NPTS * 3;
    const int mbase = chunk * CHUNKSZ;

    // Stage (-2x, -2y, -2z, |p|^2); -2.0f*x is exact.
    for (int p = tid; p < CHUNKSZ; p += TPB) {
        float x = basep[(mbase + p) * 3 + 0];
        float y = basep[(mbase + p) * 3 + 1];
        float z = basep[(mbase + p) * 3 + 2];
        pts[p] = make_float4(-2.0f * x, -2.0f * y, -2.0f * z,
                             fmaf(x, x, fmaf(y, y, z * z)));
    }

    const int qbase = tile * (TPB * Q);
    int nq[Q];
    float xn[Q], yn[Q], zn[Q], b1[Q], b2[Q];
    int i1[Q], i2[Q];
#pragma unroll
    for (int q = 0; q < Q; ++q) {
        int n = qbase + q * TPB + tid;
        nq[q] = n;
        xn[q] = basep[n * 3 + 0];
        yn[q] = basep[n * 3 + 1];
        zn[q] = basep[n * 3 + 2];
        b1[q] = BIGD; b2[q] = BIGD; i1[q] = 0; i2[q] = 0;
    }
    __syncthreads();

    // Block-uniform overlap test picks the EXC instantiation.
    const int qend = qbase + TPB * Q;
    const int mend = mbase + CHUNKSZ;
    if (mbase < qend && qbase < mend) {
        scan_loop<CHUNKSZ, Q, true >(pts, mbase, nq, xn, yn, zn, b1, i1, b2, i2);
    } else {
        scan_loop<CHUNKSZ, Q, false>(pts, mbase, nq, xn, yn, zn, b1, i1, b2, i2);
    }

    // Layout [chunk][global query] -> coalesced in both passes.
#pragma unroll
    for (int q = 0; q < Q; ++q) {
        int n = qbase + q * TPB + tid;
        partial[(size_t)chunk * TOTQ + (size_t)b * NPTS + n] =
            make_float4(b1[q], __int_as_float(i1[q]), b2[q], __int_as_float(i2[q]));
    }
}

// Pass 2: trivial merge of NCHUNKS indexed partials per query (ascending
// chunk = ascending index = stable), gather coords, write outputs.
template <int NCHUNKS>
__global__ __launch_bounds__(TPB) void knn_merge(const float* __restrict__ coords,
                                                 const float4* __restrict__ partial,
                                                 float* __restrict__ out) {
    const int q = blockIdx.x * TPB + (int)threadIdx.x;  // 0..TOTQ-1
    const int b = q >> 12;
    float b1 = BIGD, b2 = BIGD;
    int i1 = 0, i2 = 0;
#pragma unroll 8
    for (int c = 0; c < NCHUNKS; ++c) {
        float4 pc = partial[(size_t)c * TOTQ + q];
        top2min(pc.x, __float_as_int(pc.y), b1, i1, b2, i2);
        top2min(pc.z, __float_as_int(pc.w), b1, i1, b2, i2);
    }
    const float* basep = coords + (size_t)b * NPTS * 3;
    float* A  = out;
    float* C  = out + (size_t)TOTQ * 3;
    float* I1 = out + (size_t)2 * TOTQ * 3;
    float* I2 = I1 + (size_t)TOTQ;

    A[(size_t)q * 3 + 0] = basep[i1 * 3 + 0];
    A[(size_t)q * 3 + 1] = basep[i1 * 3 + 1];
    A[(size_t)q * 3 + 2] = basep[i1 * 3 + 2];
    C[(size_t)q * 3 + 0] = basep[i2 * 3 + 0];
    C[(size_t)q * 3 + 1] = basep[i2 * 3 + 1];
    C[(size_t)q * 3 + 2] = basep[i2 * 3 + 2];
    I1[q] = (float)i1;
    I2[q] = (float)i2;
}

// Fallback (tiny ws): monolithic kernel, all candidates in LDS.
__global__ __launch_bounds__(TPB) void knn_full(const float* __restrict__ coords,
                                                float* __restrict__ out) {
    __shared__ float4 pts[NPTS];  // 64 KB
    const int tid  = (int)threadIdx.x;
    const int tile = blockIdx.x;
    const int b    = blockIdx.y;
    const float* basep = coords + (size_t)b * NPTS * 3;

    for (int p = tid; p < NPTS; p += TPB) {
        float x = basep[p * 3 + 0];
        float y = basep[p * 3 + 1];
        float z = basep[p * 3 + 2];
        pts[p] = make_float4(-2.0f * x, -2.0f * y, -2.0f * z,
                             fmaf(x, x, fmaf(y, y, z * z)));
    }
    const int n = tile * TPB + tid;
    const float xn = basep[n * 3 + 0];
    const float yn = basep[n * 3 + 1];
    const float zn = basep[n * 3 + 2];
    __syncthreads();

    float b1 = BIGD, b2 = BIGD;
    int i1 = 0, i2 = 0;
    for (int p = 0; p < NPTS; p += 4) {
#pragma unroll
        for (int j = 0; j < 4; ++j) {
            float4 c = pts[p + j];
            float k = fmaf(c.x, xn, fmaf(c.y, yn, fmaf(c.z, zn, c.w)));
            k = (p + j == n) ? BIGD : k;
            top2min(k, p + j, b1, i1, b2, i2);
        }
    }

    const int q = b * NPTS + n;
    float* A  = out;
    float* C  = out + (size_t)TOTQ * 3;
    float* I1 = out + (size_t)2 * TOTQ * 3;
    float* I2 = I1 + (size_t)TOTQ;
    float4 p1 = pts[i1];
    float4 p2 = pts[i2];
    A[(size_t)q * 3 + 0] = -0.5f * p1.x;
    A[(size_t)q * 3 + 1] = -0.5f * p1.y;
    A[(size_t)q * 3 + 2] = -0.5f * p1.z;
    C[(size_t)q * 3 + 0] = -0.5f * p2.x;
    C[(size_t)q * 3 + 1] = -0.5f * p2.y;
    C[(size_t)q * 3 + 2] = -0.5f * p2.z;
    I1[q] = (float)i1;
    I2[q] = (float)i2;
}

extern "C" void kernel_launch(void* const* d_in, const int* in_sizes, int n_in,
                              void* d_out, int out_size, void* d_ws, size_t ws_size,
                              hipStream_t stream) {
    const float* coords = (const float*)d_in[0];
    float* out = (float*)d_out;
    float4* partial = (float4*)d_ws;
    const size_t chunk_bytes = (size_t)TOTQ * sizeof(float4);  // 512 KB per chunk

    if (ws_size >= 64 * chunk_bytes) {
        // 32 MB: NCHUNKS=64, Q=8 -> grid 2*64*8 = 1024 blocks (4/CU, 4 waves/SIMD)
        hipLaunchKernelGGL((knn_scan<64, 8>), dim3(2, 64, BATCH), dim3(TPB), 0, stream,
                           coords, partial);
        hipLaunchKernelGGL((knn_merge<64>), dim3(TOTQ / TPB), dim3(TPB), 0, stream,
                           coords, partial, out);
    } else if (ws_size >= 32 * chunk_bytes) {
        // 16 MB: NCHUNKS=32, Q=8 -> 512 blocks
        hipLaunchKernelGGL((knn_scan<32, 8>), dim3(2, 32, BATCH), dim3(TPB), 0, stream,
                           coords, partial);
        hipLaunchKernelGGL((knn_merge<32>), dim3(TOTQ / TPB), dim3(TPB), 0, stream,
                           coords, partial, out);
    } else {
        hipLaunchKernelGGL(knn_full, dim3(NPTS / TPB, BATCH), dim3(TPB), 0, stream,
                           coords, out);
    }
}